// Round 1
// baseline (28.815 us; speedup 1.0000x reference)
//
#include <hip/hip_runtime.h>

typedef _Float16 half2_t __attribute__((ext_vector_type(2)));
typedef float float4_t __attribute__((ext_vector_type(4)));

#define NN 2048
#define DD 32
#define HH 64
#define HP 32   // half2 pairs along h

// ---------------------------------------------------------------------------
// Kernel 1: A'[n][h] = sum_d Z[n][d] W1[d][h] + b1[h]   (B: rows D..2D-1, no b1)
// Stored transposed + h-pair-packed:  At[hp][n] = half2(A'[n][2hp], A'[n][2hp+1])
// ---------------------------------------------------------------------------
__global__ __launch_bounds__(256) void precompute_kernel(
    const float* __restrict__ Z, const float* __restrict__ W1,
    const float* __restrict__ b1, unsigned* __restrict__ At,
    unsigned* __restrict__ Bt)
{
  __shared__ float zt[64][DD];
  const int t  = threadIdx.x;
  const int isB = blockIdx.y;
  const int n0 = blockIdx.x * 64;

  // load Z rows n0..n0+63 (64x32 floats), coalesced
#pragma unroll
  for (int k = 0; k < 8; ++k) {
    int idx = t + k * 256;
    int r = idx >> 5, c = idx & 31;
    zt[r][c] = Z[(n0 + r) * DD + c];
  }
  __syncthreads();

  const int hp = t & 31;          // which h-pair
  const int nb = (t >> 5) * 8;    // 8 consecutive rows per thread
  const float* w = W1 + (isB ? DD * HH : 0);
  const float c0 = isB ? 0.f : b1[2 * hp];
  const float c1 = isB ? 0.f : b1[2 * hp + 1];

  float acc0[8], acc1[8];
#pragma unroll
  for (int k = 0; k < 8; ++k) { acc0[k] = c0; acc1[k] = c1; }

  for (int d = 0; d < DD; ++d) {
    const float w0 = w[d * HH + 2 * hp];
    const float w1 = w[d * HH + 2 * hp + 1];
#pragma unroll
    for (int k = 0; k < 8; ++k) {
      const float z = zt[nb + k][d];
      acc0[k] = fmaf(z, w0, acc0[k]);
      acc1[k] = fmaf(z, w1, acc1[k]);
    }
  }

  unsigned* outp = isB ? Bt : At;
#pragma unroll
  for (int k = 0; k < 8; ++k) {
    half2_t h;
    h.x = (_Float16)acc0[k];
    h.y = (_Float16)acc1[k];
    outp[hp * NN + n0 + nb + k] = __builtin_bit_cast(unsigned, h);
  }
}

// ---------------------------------------------------------------------------
// Kernel 2: out[i][j] = sigmoid( sum_h relu(A'[i,h]+B[j,h]) * W2[h] + b2 )
// Block: 256 threads, 64(i) x 128(j) tile, per-thread 4x8.
// Inner loop over 32 h-pairs in packed f16: pk_add + pk_max + v_dot2_f32_f16.
// ---------------------------------------------------------------------------
__global__ __launch_bounds__(256) void decoder_main(
    const unsigned* __restrict__ At, const unsigned* __restrict__ Bt,
    const float* __restrict__ W2, const float* __restrict__ b2,
    float* __restrict__ out)
{
  __shared__ unsigned Al[HP][64];    // [hp][row]  8 KB
  __shared__ unsigned Bl[HP][128];   // [hp][col] 16 KB
  __shared__ unsigned w2l[HP];

  const int t  = threadIdx.x;
  const int i0 = blockIdx.y * 64;
  const int j0 = blockIdx.x * 128;

  // stage A tile: 32x64 u32, coalesced global read, conflict-free LDS write
  {
    const int row = t & 63, hb = t >> 6;
#pragma unroll
    for (int k = 0; k < 8; ++k) {
      const int hp = hb + k * 4;
      Al[hp][row] = At[hp * NN + i0 + row];
    }
  }
  // stage B tile: 32x128 u32
  {
    const int col = t & 127, hb = t >> 7;
#pragma unroll
    for (int k = 0; k < 16; ++k) {
      const int hp = hb + k * 2;
      Bl[hp][col] = Bt[hp * NN + j0 + col];
    }
  }
  if (t < HP) {
    half2_t h;
    h.x = (_Float16)W2[2 * t];
    h.y = (_Float16)W2[2 * t + 1];
    w2l[t] = __builtin_bit_cast(unsigned, h);
  }
  __syncthreads();

  const int tx = t & 15, ty = t >> 4;   // tx -> j (8 cols), ty -> i (4 rows)

  float acc[4][8];
#pragma unroll
  for (int r = 0; r < 4; ++r)
#pragma unroll
    for (int c = 0; c < 8; ++c) acc[r][c] = 0.f;

  const half2_t zero = {(_Float16)0.f, (_Float16)0.f};

#pragma unroll 4
  for (int hp = 0; hp < HP; ++hp) {
    const uint4 av  = *reinterpret_cast<const uint4*>(&Al[hp][ty * 4]);
    const uint4 bv0 = *reinterpret_cast<const uint4*>(&Bl[hp][tx * 8]);
    const uint4 bv1 = *reinterpret_cast<const uint4*>(&Bl[hp][tx * 8 + 4]);
    const half2_t w2v = __builtin_bit_cast(half2_t, w2l[hp]);

    half2_t a[4], b[8];
    a[0] = __builtin_bit_cast(half2_t, av.x);
    a[1] = __builtin_bit_cast(half2_t, av.y);
    a[2] = __builtin_bit_cast(half2_t, av.z);
    a[3] = __builtin_bit_cast(half2_t, av.w);
    b[0] = __builtin_bit_cast(half2_t, bv0.x);
    b[1] = __builtin_bit_cast(half2_t, bv0.y);
    b[2] = __builtin_bit_cast(half2_t, bv0.z);
    b[3] = __builtin_bit_cast(half2_t, bv0.w);
    b[4] = __builtin_bit_cast(half2_t, bv1.x);
    b[5] = __builtin_bit_cast(half2_t, bv1.y);
    b[6] = __builtin_bit_cast(half2_t, bv1.z);
    b[7] = __builtin_bit_cast(half2_t, bv1.w);

#pragma unroll
    for (int r = 0; r < 4; ++r)
#pragma unroll
      for (int c = 0; c < 8; ++c) {
        half2_t s = a[r] + b[c];                       // v_pk_add_f16
        s = __builtin_elementwise_max(s, zero);        // v_pk_max_f16 (relu)
        acc[r][c] = __builtin_amdgcn_fdot2(s, w2v, acc[r][c], false); // v_dot2_f32_f16
      }
  }

  const float b2v = b2[0];
#pragma unroll
  for (int r = 0; r < 4; ++r) {
    float* o = out + (size_t)(i0 + ty * 4 + r) * NN + j0 + tx * 8;
    float y[8];
#pragma unroll
    for (int c = 0; c < 8; ++c) {
      const float x = acc[r][c] + b2v;
      y[c] = 1.0f / (1.0f + __expf(-x));
    }
    float4_t v0 = {y[0], y[1], y[2], y[3]};
    float4_t v1 = {y[4], y[5], y[6], y[7]};
    *reinterpret_cast<float4_t*>(o)     = v0;
    *reinterpret_cast<float4_t*>(o + 4) = v1;
  }
}

extern "C" void kernel_launch(void* const* d_in, const int* in_sizes, int n_in,
                              void* d_out, int out_size, void* d_ws, size_t ws_size,
                              hipStream_t stream) {
  const float* Z  = (const float*)d_in[0];
  const float* W1 = (const float*)d_in[1];
  const float* b1 = (const float*)d_in[2];
  const float* W2 = (const float*)d_in[3];
  const float* b2 = (const float*)d_in[4];
  float* out = (float*)d_out;

  unsigned* At = (unsigned*)d_ws;          // 32*2048 u32 = 256 KB
  unsigned* Bt = At + HP * NN;             // 256 KB more

  dim3 pgrid(NN / 64, 2);
  precompute_kernel<<<pgrid, 256, 0, stream>>>(Z, W1, b1, At, Bt);

  dim3 mgrid(NN / 128, NN / 64);           // (j-tiles, i-tiles) = (16, 32)
  decoder_main<<<mgrid, 256, 0, stream>>>(At, Bt, W2, b2, out);
}

// Round 2
// 27.310 us; speedup vs baseline: 1.0551x; 1.0551x over previous
//
#include <hip/hip_runtime.h>

typedef _Float16 half2_t __attribute__((ext_vector_type(2)));
typedef float float4_t __attribute__((ext_vector_type(4)));

#define NN 2048
#define DD 32
#define HH 64
#define HP 32            // half2 pairs along h
#define SCALE 0.0625f    // store (A+b1)/16, B/16 so clamp == relu
#define ISCALE 16.0f     // folded back into w2

// ---------------------------------------------------------------------------
// Kernel 1: A'[n][h] = sum_d Z[n][d] W1[d][h] + b1[h]  (B half: rows D..2D-1)
// Stored transposed, h-pair packed f16, scaled by 1/16:
//   At[hp][n] = half2(A'[n][2hp], A'[n][2hp+1]) * SCALE
// Coalesced global stores via padded-LDS transpose bounce.
// ---------------------------------------------------------------------------
__global__ __launch_bounds__(256) void precompute_kernel(
    const float* __restrict__ Z, const float* __restrict__ W1,
    const float* __restrict__ b1, unsigned* __restrict__ At,
    unsigned* __restrict__ Bt)
{
  __shared__ float zt[32][DD];       // 4 KB
  __shared__ unsigned st[HP][33];    // padded: +1 breaks bank aliasing
  const int t   = threadIdx.x;
  const int isB = blockIdx.y;
  const int n0  = blockIdx.x * 32;

#pragma unroll
  for (int k = 0; k < 4; ++k) {
    const int idx = t + k * 256;
    zt[idx >> 5][idx & 31] = Z[(n0 + (idx >> 5)) * DD + (idx & 31)];
  }
  __syncthreads();

  const int hp = t & 31;
  const int nb = (t >> 5) * 4;       // 4 rows per thread
  const float* w = W1 + (isB ? DD * HH : 0);
  const float c0 = isB ? 0.f : b1[2 * hp];
  const float c1 = isB ? 0.f : b1[2 * hp + 1];

  float acc0[4], acc1[4];
#pragma unroll
  for (int k = 0; k < 4; ++k) { acc0[k] = c0; acc1[k] = c1; }

  for (int d = 0; d < DD; ++d) {
    const float w0 = w[d * HH + 2 * hp];
    const float w1 = w[d * HH + 2 * hp + 1];
#pragma unroll
    for (int k = 0; k < 4; ++k) {
      const float z = zt[nb + k][d];
      acc0[k] = fmaf(z, w0, acc0[k]);
      acc1[k] = fmaf(z, w1, acc1[k]);
    }
  }

#pragma unroll
  for (int k = 0; k < 4; ++k) {
    half2_t h;
    h.x = (_Float16)(acc0[k] * SCALE);
    h.y = (_Float16)(acc1[k] * SCALE);
    st[hp][nb + k] = __builtin_bit_cast(unsigned, h);
  }
  __syncthreads();

  unsigned* outp = isB ? Bt : At;
#pragma unroll
  for (int k = 0; k < 4; ++k) {
    const int idx = t + k * 256;          // 32x32 u32 tile
    const int r = idx >> 5, c = idx & 31;
    outp[r * NN + n0 + c] = st[r][c];     // 64 lanes -> 2 contiguous 128B runs
  }
}

// ---------------------------------------------------------------------------
// Kernel 2: out[i][j] = sigmoid( 16 * sum_hp dot2(clamp(a+b), w2') + b2 )
// 64(i) x 128(j) tile per 256-thread block; per-thread 4x8 (j split 4+4).
// Inner: v_pk_add_f16 clamp  +  v_dot2_f32_f16  = 2 VALU per h-pair.
// ---------------------------------------------------------------------------
__global__ __launch_bounds__(256, 2) void decoder_main(
    const unsigned* __restrict__ At, const unsigned* __restrict__ Bt,
    const float* __restrict__ W2, const float* __restrict__ b2,
    float* __restrict__ out)
{
  __shared__ unsigned Al[HP][64];    //  8 KB
  __shared__ unsigned Bl[HP][128];   // 16 KB

  const int t  = threadIdx.x;
  const int i0 = blockIdx.y * 64;
  const int j0 = blockIdx.x * 128;

  // stage A tile (32x64 u32): coalesced 256B wave reads
  {
    const int row = t & 63, hb = t >> 6;
#pragma unroll
    for (int k = 0; k < 8; ++k) {
      const int hp = hb + k * 4;
      Al[hp][row] = At[hp * NN + i0 + row];
    }
  }
  // stage B tile (32x128 u32)
  {
    const int col = t & 127, hb = t >> 7;
#pragma unroll
    for (int k = 0; k < 16; ++k) {
      const int hp = hb + k * 2;
      Bl[hp][col] = Bt[hp * NN + j0 + col];
    }
  }

  // w2 (x16) packed to half2, held in VGPRs; uniform scalar loads
  half2_t w2h[HP];
#pragma unroll
  for (int p = 0; p < HP; ++p) {
    half2_t h;
    h.x = (_Float16)(W2[2 * p] * ISCALE);
    h.y = (_Float16)(W2[2 * p + 1] * ISCALE);
    w2h[p] = h;
  }
  __syncthreads();

  const int tx = t & 15, ty = t >> 4;   // tx -> j (4+4 cols), ty -> i (4 rows)

  float acc[4][8];
#pragma unroll
  for (int r = 0; r < 4; ++r)
#pragma unroll
    for (int c = 0; c < 8; ++c) acc[r][c] = 0.f;

#pragma unroll
  for (int hp = 0; hp < HP; ++hp) {
    // 16B reads at 16B lane stride -> 2-way bank alias (free)
    const uint4 av  = *reinterpret_cast<const uint4*>(&Al[hp][ty * 4]);
    const uint4 bv0 = *reinterpret_cast<const uint4*>(&Bl[hp][tx * 4]);
    const uint4 bv1 = *reinterpret_cast<const uint4*>(&Bl[hp][64 + tx * 4]);

    half2_t a[4], b[8];
    a[0] = __builtin_bit_cast(half2_t, av.x);
    a[1] = __builtin_bit_cast(half2_t, av.y);
    a[2] = __builtin_bit_cast(half2_t, av.z);
    a[3] = __builtin_bit_cast(half2_t, av.w);
    b[0] = __builtin_bit_cast(half2_t, bv0.x);
    b[1] = __builtin_bit_cast(half2_t, bv0.y);
    b[2] = __builtin_bit_cast(half2_t, bv0.z);
    b[3] = __builtin_bit_cast(half2_t, bv0.w);
    b[4] = __builtin_bit_cast(half2_t, bv1.x);
    b[5] = __builtin_bit_cast(half2_t, bv1.y);
    b[6] = __builtin_bit_cast(half2_t, bv1.z);
    b[7] = __builtin_bit_cast(half2_t, bv1.w);

    const half2_t w2v = w2h[hp];
#pragma unroll
    for (int r = 0; r < 4; ++r)
#pragma unroll
      for (int c = 0; c < 8; ++c) {
        half2_t s;
        // clamp to [0,1]: inputs scaled so max < 1 -> acts as relu
        asm("v_pk_add_f16 %0, %1, %2 clamp" : "=v"(s) : "v"(a[r]), "v"(b[c]));
        acc[r][c] = __builtin_amdgcn_fdot2(s, w2v, acc[r][c], false);
      }
  }

  const float b2v = b2[0];
#pragma unroll
  for (int r = 0; r < 4; ++r) {
    float y[8];
#pragma unroll
    for (int c = 0; c < 8; ++c) {
      const float x = acc[r][c] + b2v;
      y[c] = 1.0f / (1.0f + __expf(-x));
    }
    float* o = out + (size_t)(i0 + ty * 4 + r) * NN + j0 + tx * 4;
    float4_t v0 = {y[0], y[1], y[2], y[3]};
    float4_t v1 = {y[4], y[5], y[6], y[7]};
    *reinterpret_cast<float4_t*>(o)      = v0;   // cols j0 + tx*4
    *reinterpret_cast<float4_t*>(o + 64) = v1;   // cols j0 + 64 + tx*4
  }
}

extern "C" void kernel_launch(void* const* d_in, const int* in_sizes, int n_in,
                              void* d_out, int out_size, void* d_ws, size_t ws_size,
                              hipStream_t stream) {
  const float* Z  = (const float*)d_in[0];
  const float* W1 = (const float*)d_in[1];
  const float* b1 = (const float*)d_in[2];
  const float* W2 = (const float*)d_in[3];
  const float* b2 = (const float*)d_in[4];
  float* out = (float*)d_out;

  unsigned* At = (unsigned*)d_ws;          // 32*2048 u32 = 256 KB
  unsigned* Bt = At + HP * NN;             // 256 KB

  dim3 pgrid(NN / 32, 2);                  // 128 blocks
  precompute_kernel<<<pgrid, 256, 0, stream>>>(Z, W1, b1, At, Bt);

  dim3 mgrid(NN / 128, NN / 64);           // 16 x 32 = 512 blocks
  decoder_main<<<mgrid, 256, 0, stream>>>(At, Bt, W2, b2, out);
}

// Round 8
// 26.650 us; speedup vs baseline: 1.0812x; 1.0248x over previous
//
#include <hip/hip_runtime.h>

typedef _Float16 half2_t __attribute__((ext_vector_type(2)));
typedef float float4_t __attribute__((ext_vector_type(4)));

#define NN 2048
#define DD 32
#define HH 64
#define HP 32            // half2 pairs along h
#define SCALE 0.0625f    // store (A+b1)/16, B/16 so clamp == relu
#define ISCALE 16.0f     // folded back into w2

// ---------------------------------------------------------------------------
// Kernel 1 (identical to R2 run): A'[n][h] = Z@W1[:D] + b1 ; B = Z@W1[D:]
// Stored transposed, h-pair packed f16, scaled by 1/16: At[hp][n]
// ---------------------------------------------------------------------------
__global__ __launch_bounds__(256) void precompute_kernel(
    const float* __restrict__ Z, const float* __restrict__ W1,
    const float* __restrict__ b1, unsigned* __restrict__ At,
    unsigned* __restrict__ Bt)
{
  __shared__ float zt[32][DD];       // 4 KB
  __shared__ unsigned st[HP][33];    // padded transpose bounce
  const int t   = threadIdx.x;
  const int isB = blockIdx.y;
  const int n0  = blockIdx.x * 32;

#pragma unroll
  for (int k = 0; k < 4; ++k) {
    const int idx = t + k * 256;
    zt[idx >> 5][idx & 31] = Z[(n0 + (idx >> 5)) * DD + (idx & 31)];
  }
  __syncthreads();

  const int hp = t & 31;
  const int nb = (t >> 5) * 4;       // 4 rows per thread
  const float* w = W1 + (isB ? DD * HH : 0);
  const float c0 = isB ? 0.f : b1[2 * hp];
  const float c1 = isB ? 0.f : b1[2 * hp + 1];

  float acc0[4], acc1[4];
#pragma unroll
  for (int k = 0; k < 4; ++k) { acc0[k] = c0; acc1[k] = c1; }

  for (int d = 0; d < DD; ++d) {
    const float w0 = w[d * HH + 2 * hp];
    const float w1 = w[d * HH + 2 * hp + 1];
#pragma unroll
    for (int k = 0; k < 4; ++k) {
      const float z = zt[nb + k][d];
      acc0[k] = fmaf(z, w0, acc0[k]);
      acc1[k] = fmaf(z, w1, acc1[k]);
    }
  }

#pragma unroll
  for (int k = 0; k < 4; ++k) {
    half2_t h;
    h.x = (_Float16)(acc0[k] * SCALE);
    h.y = (_Float16)(acc1[k] * SCALE);
    st[hp][nb + k] = __builtin_bit_cast(unsigned, h);
  }
  __syncthreads();

  unsigned* outp = isB ? Bt : At;
#pragma unroll
  for (int k = 0; k < 4; ++k) {
    const int idx = t + k * 256;          // 32x32 u32 tile
    const int r = idx >> 5, c = idx & 31;
    outp[r * NN + n0 + c] = st[r][c];
  }
}

// ---------------------------------------------------------------------------
// Kernel 2: 64(i) x 64(j) tile, 256 threads, per-thread 4x4.
// 1024 blocks -> 4 blocks/CU -> 4 waves/SIMD (occupancy lever vs R2's 2).
// Plain R2-style inner loop; 4-wave TLP hides per-hp lgkmcnt waits.
// (Resubmission — rounds 3-7 died to pod-side disk-full, not kernel.)
// ---------------------------------------------------------------------------
__global__ __launch_bounds__(256, 4) void decoder_main(
    const unsigned* __restrict__ At, const unsigned* __restrict__ Bt,
    const float* __restrict__ W2, const float* __restrict__ b2,
    float* __restrict__ out)
{
  __shared__ unsigned Al[HP][64];    // 8 KB
  __shared__ unsigned Bl[HP][64];    // 8 KB

  const int t  = threadIdx.x;
  const int i0 = blockIdx.y * 64;
  const int j0 = blockIdx.x * 64;

  // stage both 32x64 u32 tiles: scalar u32 per thread, coalesced
  {
    const int col = t & 63, hb = t >> 6;
#pragma unroll
    for (int k = 0; k < 8; ++k) {
      const int hp = hb + k * 4;
      Al[hp][col] = At[hp * NN + i0 + col];
      Bl[hp][col] = Bt[hp * NN + j0 + col];
    }
  }

  // w2 (x16) packed to half2; uniform -> scalar regs
  half2_t w2h[HP];
#pragma unroll
  for (int p = 0; p < HP; ++p) {
    half2_t h;
    h.x = (_Float16)(W2[2 * p] * ISCALE);
    h.y = (_Float16)(W2[2 * p + 1] * ISCALE);
    w2h[p] = h;
  }
  __syncthreads();

  const int tx = t & 15, ty = t >> 4;   // tx -> j (4 cols), ty -> i (4 rows)

  float acc[4][4];
#pragma unroll
  for (int r = 0; r < 4; ++r)
#pragma unroll
    for (int c = 0; c < 4; ++c) acc[r][c] = 0.f;

#pragma unroll
  for (int hp = 0; hp < HP; ++hp) {
    const uint4 av = *reinterpret_cast<const uint4*>(&Al[hp][ty * 4]);
    const uint4 bv = *reinterpret_cast<const uint4*>(&Bl[hp][tx * 4]);

    half2_t a[4], b[4];
    a[0] = __builtin_bit_cast(half2_t, av.x);
    a[1] = __builtin_bit_cast(half2_t, av.y);
    a[2] = __builtin_bit_cast(half2_t, av.z);
    a[3] = __builtin_bit_cast(half2_t, av.w);
    b[0] = __builtin_bit_cast(half2_t, bv.x);
    b[1] = __builtin_bit_cast(half2_t, bv.y);
    b[2] = __builtin_bit_cast(half2_t, bv.z);
    b[3] = __builtin_bit_cast(half2_t, bv.w);

    const half2_t w2v = w2h[hp];
#pragma unroll
    for (int r = 0; r < 4; ++r)
#pragma unroll
      for (int c = 0; c < 4; ++c) {
        half2_t s;
        // clamp to [0,1]: inputs scaled so max < 1 -> acts as relu
        asm("v_pk_add_f16 %0, %1, %2 clamp" : "=v"(s) : "v"(a[r]), "v"(b[c]));
        acc[r][c] = __builtin_amdgcn_fdot2(s, w2v, acc[r][c], false);
      }
  }

  const float b2v = b2[0];
#pragma unroll
  for (int r = 0; r < 4; ++r) {
    float y[4];
#pragma unroll
    for (int c = 0; c < 4; ++c) {
      const float x = acc[r][c] + b2v;
      y[c] = 1.0f / (1.0f + __expf(-x));
    }
    float* o = out + (size_t)(i0 + ty * 4 + r) * NN + j0 + tx * 4;
    float4_t v = {y[0], y[1], y[2], y[3]};
    *reinterpret_cast<float4_t*>(o) = v;
  }
}

extern "C" void kernel_launch(void* const* d_in, const int* in_sizes, int n_in,
                              void* d_out, int out_size, void* d_ws, size_t ws_size,
                              hipStream_t stream) {
  const float* Z  = (const float*)d_in[0];
  const float* W1 = (const float*)d_in[1];
  const float* b1 = (const float*)d_in[2];
  const float* W2 = (const float*)d_in[3];
  const float* b2 = (const float*)d_in[4];
  float* out = (float*)d_out;

  unsigned* At = (unsigned*)d_ws;          // 32*2048 u32 = 256 KB
  unsigned* Bt = At + HP * NN;             // 256 KB

  dim3 pgrid(NN / 32, 2);                  // 128 blocks
  precompute_kernel<<<pgrid, 256, 0, stream>>>(Z, W1, b1, At, Bt);

  dim3 mgrid(NN / 64, NN / 64);            // 32 x 32 = 1024 blocks
  decoder_main<<<mgrid, 256, 0, stream>>>(At, Bt, W2, b2, out);
}

// Round 9
// 25.327 us; speedup vs baseline: 1.1377x; 1.0523x over previous
//
#include <hip/hip_runtime.h>

typedef _Float16 half2_t __attribute__((ext_vector_type(2)));
typedef float float4_t __attribute__((ext_vector_type(4)));

#define NN 2048
#define DD 32
#define HH 64
#define HP 32            // half2 pairs along h
#define SCALE 0.0625f    // store (A+b1)/16, B/16 so clamp == relu
#define ISCALE 16.0f     // folded back into w2

// ---------------------------------------------------------------------------
// Kernel 1 (unchanged): A'[n][h] = Z@W1[:D] + b1 ; B = Z@W1[D:]
// Stored transposed, h-pair packed f16, scaled by 1/16: At[hp][n]
// ---------------------------------------------------------------------------
__global__ __launch_bounds__(256) void precompute_kernel(
    const float* __restrict__ Z, const float* __restrict__ W1,
    const float* __restrict__ b1, unsigned* __restrict__ At,
    unsigned* __restrict__ Bt)
{
  __shared__ float zt[32][DD];       // 4 KB
  __shared__ unsigned st[HP][33];    // padded transpose bounce
  const int t   = threadIdx.x;
  const int isB = blockIdx.y;
  const int n0  = blockIdx.x * 32;

#pragma unroll
  for (int k = 0; k < 4; ++k) {
    const int idx = t + k * 256;
    zt[idx >> 5][idx & 31] = Z[(n0 + (idx >> 5)) * DD + (idx & 31)];
  }
  __syncthreads();

  const int hp = t & 31;
  const int nb = (t >> 5) * 4;       // 4 rows per thread
  const float* w = W1 + (isB ? DD * HH : 0);
  const float c0 = isB ? 0.f : b1[2 * hp];
  const float c1 = isB ? 0.f : b1[2 * hp + 1];

  float acc0[4], acc1[4];
#pragma unroll
  for (int k = 0; k < 4; ++k) { acc0[k] = c0; acc1[k] = c1; }

  for (int d = 0; d < DD; ++d) {
    const float w0 = w[d * HH + 2 * hp];
    const float w1 = w[d * HH + 2 * hp + 1];
#pragma unroll
    for (int k = 0; k < 4; ++k) {
      const float z = zt[nb + k][d];
      acc0[k] = fmaf(z, w0, acc0[k]);
      acc1[k] = fmaf(z, w1, acc1[k]);
    }
  }

#pragma unroll
  for (int k = 0; k < 4; ++k) {
    half2_t h;
    h.x = (_Float16)(acc0[k] * SCALE);
    h.y = (_Float16)(acc1[k] * SCALE);
    st[hp][nb + k] = __builtin_bit_cast(unsigned, h);
  }
  __syncthreads();

  unsigned* outp = isB ? Bt : At;
#pragma unroll
  for (int k = 0; k < 4; ++k) {
    const int idx = t + k * 256;          // 32x32 u32 tile
    const int r = idx >> 5, c = idx & 31;
    outp[r * NN + n0 + c] = st[r][c];
  }
}

// ---------------------------------------------------------------------------
// Kernel 2: 64x64 tile, 256 threads, per-thread 4x4, 4 blocks/CU.
// KEY CHANGE vs R8: packed w2 words are wave-uniform -> forced into SGPRs
// via readfirstlane (R2/R8 kept them in a VGPR array that spilled at
// VGPR_Count=40, causing per-hp rematerialization = 3x VALU + stalls).
// Epilogue: sigmoid via exp2 + v_rcp instead of IEEE divide.
// ---------------------------------------------------------------------------
__global__ __launch_bounds__(256, 4) void decoder_main(
    const unsigned* __restrict__ At, const unsigned* __restrict__ Bt,
    const float* __restrict__ W2, const float* __restrict__ b2,
    float* __restrict__ out)
{
  __shared__ unsigned Al[HP][64];    // 8 KB
  __shared__ unsigned Bl[HP][64];    // 8 KB

  const int t  = threadIdx.x;
  const int i0 = blockIdx.y * 64;
  const int j0 = blockIdx.x * 64;

  // stage both 32x64 u32 tiles: scalar u32 per thread, coalesced
  {
    const int col = t & 63, hb = t >> 6;
#pragma unroll
    for (int k = 0; k < 8; ++k) {
      const int hp = hb + k * 4;
      Al[hp][col] = At[hp * NN + i0 + col];
      Bl[hp][col] = Bt[hp * NN + j0 + col];
    }
  }

  // w2 (x16) packed to half2 -> SGPRs via readfirstlane (wave-uniform)
  unsigned w2u[HP];
#pragma unroll
  for (int p = 0; p < HP; ++p) {
    half2_t h;
    h.x = (_Float16)(W2[2 * p] * ISCALE);
    h.y = (_Float16)(W2[2 * p + 1] * ISCALE);
    w2u[p] = __builtin_amdgcn_readfirstlane(__builtin_bit_cast(unsigned, h));
  }
  __syncthreads();

  const int tx = t & 15, ty = t >> 4;   // tx -> j (4 cols), ty -> i (4 rows)

  float acc[4][4];
#pragma unroll
  for (int r = 0; r < 4; ++r)
#pragma unroll
    for (int c = 0; c < 4; ++c) acc[r][c] = 0.f;

#pragma unroll
  for (int hp = 0; hp < HP; ++hp) {
    const uint4 av = *reinterpret_cast<const uint4*>(&Al[hp][ty * 4]);
    const uint4 bv = *reinterpret_cast<const uint4*>(&Bl[hp][tx * 4]);

    half2_t a[4], b[4];
    a[0] = __builtin_bit_cast(half2_t, av.x);
    a[1] = __builtin_bit_cast(half2_t, av.y);
    a[2] = __builtin_bit_cast(half2_t, av.z);
    a[3] = __builtin_bit_cast(half2_t, av.w);
    b[0] = __builtin_bit_cast(half2_t, bv.x);
    b[1] = __builtin_bit_cast(half2_t, bv.y);
    b[2] = __builtin_bit_cast(half2_t, bv.z);
    b[3] = __builtin_bit_cast(half2_t, bv.w);

    const half2_t w2v = __builtin_bit_cast(half2_t, w2u[hp]);
#pragma unroll
    for (int r = 0; r < 4; ++r)
#pragma unroll
      for (int c = 0; c < 4; ++c) {
        half2_t s;
        // clamp to [0,1]: inputs scaled so max < 1 -> acts as relu
        asm("v_pk_add_f16 %0, %1, %2 clamp" : "=v"(s) : "v"(a[r]), "v"(b[c]));
        acc[r][c] = __builtin_amdgcn_fdot2(s, w2v, acc[r][c], false);
      }
  }

  const float b2v = b2[0];
  const float NLOG2E = -1.44269504f;
#pragma unroll
  for (int r = 0; r < 4; ++r) {
    float y[4];
#pragma unroll
    for (int c = 0; c < 4; ++c) {
      const float x = acc[r][c] + b2v;
      const float e = __builtin_amdgcn_exp2f(x * NLOG2E);   // e^{-x}
      y[c] = __builtin_amdgcn_rcpf(1.0f + e);               // sigmoid
    }
    float* o = out + (size_t)(i0 + ty * 4 + r) * NN + j0 + tx * 4;
    float4_t v = {y[0], y[1], y[2], y[3]};
    *reinterpret_cast<float4_t*>(o) = v;
  }
}

extern "C" void kernel_launch(void* const* d_in, const int* in_sizes, int n_in,
                              void* d_out, int out_size, void* d_ws, size_t ws_size,
                              hipStream_t stream) {
  const float* Z  = (const float*)d_in[0];
  const float* W1 = (const float*)d_in[1];
  const float* b1 = (const float*)d_in[2];
  const float* W2 = (const float*)d_in[3];
  const float* b2 = (const float*)d_in[4];
  float* out = (float*)d_out;

  unsigned* At = (unsigned*)d_ws;          // 32*2048 u32 = 256 KB
  unsigned* Bt = At + HP * NN;             // 256 KB

  dim3 pgrid(NN / 32, 2);                  // 128 blocks
  precompute_kernel<<<pgrid, 256, 0, stream>>>(Z, W1, b1, At, Bt);

  dim3 mgrid(NN / 64, NN / 64);            // 32 x 32 = 1024 blocks
  decoder_main<<<mgrid, 256, 0, stream>>>(At, Bt, W2, b2, out);
}